// Round 8
// baseline (262.691 us; speedup 1.0000x reference)
//
#include <hip/hip_runtime.h>
#include <stdint.h>

typedef uint32_t u32;
typedef __attribute__((ext_vector_type(4))) float f32x4;
typedef __attribute__((ext_vector_type(8))) short short8;

#define NBATCH 16
#define NPIX   16384      // H*W
#define NPB    1048576    // per-batch flat elems (C*H*W = 1024*1024)

__device__ __forceinline__ ushort f2bf(float f) {
  u32 b = __builtin_bit_cast(u32, f);
  return (ushort)((b + 0x7FFFu + ((b >> 16) & 1u)) >> 16);
}
__device__ __forceinline__ float bf2f(ushort h) {
  return __builtin_bit_cast(float, (u32)h << 16);
}

// async global->LDS, 16B per lane. LDS dest must be wave-uniform base;
// HW scatters lane i at base + i*16.
__device__ __forceinline__ void gload16(const ushort* g, ushort* l) {
  __builtin_amdgcn_global_load_lds(
      (const __attribute__((address_space(1))) u32*)(const void*)g,
      (__attribute__((address_space(3))) u32*)(void*)l,
      16, 0, 0);
}

// ---------------- Kernel 1: projections (weights in LDS, 2-phase x) ----------
// Block = 320 threads (5 waves), one 128-pixel tile. Weights [80][64] staged
// in LDS (broadcast ds_read_b128 per (o,cb) -> no SMEM-latency serialization,
// the R7 bottleneck). x staged fp32 in two [32ch][128px] 16KB phases ->
// 36.6KB LDS -> 4 blocks/CU (20 waves) vs 32KB/36% before. Wave w = output
// group: w==0 -> q+k (split-bf16), w==1..4 -> 16 V channels each.
__global__ __launch_bounds__(320) void proj5(
    const float* __restrict__ x,
    const float* __restrict__ Wq, const float* __restrict__ bq,
    const float* __restrict__ Wk, const float* __restrict__ bk,
    const float* __restrict__ Wv, const float* __restrict__ bv,
    ushort* __restrict__ Qt2, ushort* __restrict__ Kt2,
    ushort* __restrict__ Vnat)
{
  __shared__ float wlds[80 * 64];   // [o][ch]
  __shared__ float blds[80];
  __shared__ float xs[32][128];
  int t = threadIdx.x;
  int b = blockIdx.x >> 7;
  int p0 = (blockIdx.x & 127) << 7;
  const float* xb = x + (size_t)b * NPB;

  for (int i = t; i < 5120; i += 320) {
    int o = i >> 6, c = i & 63;
    float v = (o < 8) ? Wq[o * 64 + c]
            : (o < 16) ? Wk[(o - 8) * 64 + c]
                       : Wv[(o - 16) * 64 + c];
    wlds[i] = v;
  }
  if (t < 80) blds[t] = (t < 8) ? bq[t] : (t < 16 ? bk[t - 8] : bv[t - 16]);

  int w = t >> 6, j = t & 63;
  int ob = __builtin_amdgcn_readfirstlane(w * 16);

  __syncthreads();   // w/b staged (xs phase 0 staged below)

  float acc[16][2];
  #pragma unroll
  for (int o = 0; o < 16; ++o) { float bb = blds[ob + o]; acc[o][0] = bb; acc[o][1] = bb; }

  const f32x4* wl4 = (const f32x4*)wlds;
  for (int ph = 0; ph < 2; ++ph) {
    for (int i = t; i < 4096; i += 320) {
      int ch = i >> 7, px = i & 127;
      xs[ch][px] = xb[(size_t)(ph * 32 + ch) * NPIX + p0 + px];
    }
    __syncthreads();
    for (int cb = 0; cb < 8; ++cb) {
      float2 xv0 = *(const float2*)&xs[cb * 4 + 0][j * 2];
      float2 xv1 = *(const float2*)&xs[cb * 4 + 1][j * 2];
      float2 xv2 = *(const float2*)&xs[cb * 4 + 2][j * 2];
      float2 xv3 = *(const float2*)&xs[cb * 4 + 3][j * 2];
      #pragma unroll
      for (int o = 0; o < 16; ++o) {
        f32x4 wv = wl4[(ob + o) * 16 + ph * 8 + cb];
        acc[o][0] += wv[0] * xv0.x + wv[1] * xv1.x + wv[2] * xv2.x + wv[3] * xv3.x;
        acc[o][1] += wv[0] * xv0.y + wv[1] * xv1.y + wv[2] * xv2.y + wv[3] * xv3.y;
      }
    }
    __syncthreads();   // compute done before next phase overwrites xs
  }

  if (w == 0) {
    // Q/K split bf16: Q = [qh][ql][qh], K = [kh][kh][kl] so that
    // dot = qh*kh + ql*kh + qh*kl (drops only ~2e-4 ql*kl term).
    #pragma unroll
    for (int i = 0; i < 2; ++i) {
      int p = p0 + j * 2 + i;
      int l = p & 1023, tc = p >> 10;
      union { ushort s[8]; uint4 q; } qh, ql, kh, kl;
      #pragma unroll
      for (int o = 0; o < 8; ++o) {
        float qv = acc[o][i];
        ushort h = f2bf(qv);
        qh.s[o] = h; ql.s[o] = f2bf(qv - bf2f(h));
        float kv = acc[8 + o][i];
        h = f2bf(kv);
        kh.s[o] = h; kl.s[o] = f2bf(kv - bf2f(h));
      }
      ushort* qrow = Qt2 + ((size_t)b * 1024 + l) * 384 + tc * 8;
      *(uint4*)qrow         = qh.q;
      *(uint4*)(qrow + 128) = ql.q;
      *(uint4*)(qrow + 256) = qh.q;
      ushort* krow = Kt2 + ((size_t)b * 1024 + l) * 384 + tc * 8;
      *(uint4*)krow         = kh.q;
      *(uint4*)(krow + 128) = kh.q;
      *(uint4*)(krow + 256) = kl.q;
    }
  } else {
    int cbase = ob - 16;
    ushort* vb = Vnat + (size_t)b * NPB + (size_t)cbase * NPIX + p0 + j * 2;
    #pragma unroll
    for (int c = 0; c < 16; ++c) {
      u32 pk = (u32)f2bf(acc[c][0]) | ((u32)f2bf(acc[c][1]) << 16);
      *(u32*)(vb + (size_t)c * NPIX) = pk;
    }
  }
}

// ---------------- Kernel 2: V transpose --------------------------------------
// Vt[a][p'] = Vnat_flat[p'*1024 + a]
__global__ __launch_bounds__(256) void transpose_v(
    const ushort* __restrict__ Vnat, ushort* __restrict__ Vt)
{
  __shared__ ushort tile[64][80];
  int b = blockIdx.y;
  int p0 = (blockIdx.x >> 4) << 6;
  int c0 = (blockIdx.x & 15) << 6;
  int t = threadIdx.x;
  int pr = t >> 2, ch = t & 3;
  int p = p0 + pr;
  const ushort* src = Vnat + (size_t)b * NPB + (size_t)(p >> 4) * NPIX +
                      (size_t)(p & 15) * 1024 + c0 + ch * 16;
  uint4 v0 = ((const uint4*)src)[0];
  uint4 v1 = ((const uint4*)src)[1];
  *(uint4*)&tile[pr][ch * 16] = v0;
  *(uint4*)&tile[pr][ch * 16 + 8] = v1;
  __syncthreads();
  int cl = t >> 2, pch = t & 3;
  union { ushort s[16]; uint4 q[2]; } outv;
  #pragma unroll
  for (int j = 0; j < 16; ++j) outv.s[j] = tile[pch * 16 + j][cl];
  ushort* dst = Vt + (size_t)b * NPB + (size_t)(c0 + cl) * 1024 + p0 + pch * 16;
  ((uint4*)dst)[0] = outv.q[0];
  ((uint4*)dst)[1] = outv.q[1];
}

// ---------------- Kernels 3/5: NT bf16 MFMA GEMM (m97 + src-side swizzle) ----
// C[i][j] = sum_k A[i][k]*B[j][k]; per-batch 1024x1024, tile 128x128, BK=64.
// global_load_lds width-16 staging, LINEAR LDS dest, global SOURCE chunk
// XOR-pre-swizzled (chunk' = chunk ^ (row&7)) with the same XOR on fragment
// reads -> bank-conflict-free. XCD-chunked 1D grid (2 batches per XCD).
template<int KTOT, bool ADDX>
__global__ __launch_bounds__(256) void gemm_nt(
    const ushort* __restrict__ A, int lda,
    const ushort* __restrict__ B, int ldb,
    float* __restrict__ C, const float* __restrict__ X)
{
  __shared__ ushort Asm[128 * 64];
  __shared__ ushort Bsm[128 * 64];
  int t = threadIdx.x;

  // bijective XCD-chunk remap (1024 blocks, 8 XCDs, 128 each = 2 batches)
  int g = blockIdx.x;
  int lin = (g & 7) * 128 + (g >> 3);
  int bz = lin >> 6;
  int by = (lin >> 3) & 7;
  int bx = lin & 7;
  int m0 = by << 7, n0 = bx << 7;

  const ushort* Ab = A + (size_t)bz * 1024 * lda;
  const ushort* Bb = B + (size_t)bz * 1024 * ldb;
  int wid = t >> 6, lane = t & 63;
  int wm = wid >> 1, wn = wid & 1;

  int swc = (t & 7) ^ ((t >> 3) & 7);
  const ushort* pa = Ab + (size_t)(m0 + (t >> 3)) * lda + swc * 8;
  const ushort* pb = Bb + (size_t)(n0 + (t >> 3)) * ldb + swc * 8;
  ushort* la0 = Asm + (size_t)(t >> 6) * 512;   // wave base, elems (1024 B)
  ushort* lb0 = Bsm + (size_t)(t >> 6) * 512;

  f32x4 acc[4][4] = {};

  for (int k0 = 0; k0 < KTOT; k0 += 64) {
    __syncthreads();                 // previous compute done before overwrite
    #pragma unroll
    for (int i = 0; i < 4; ++i)
      gload16(pa + (size_t)i * 32 * lda + k0, la0 + i * 2048);
    #pragma unroll
    for (int i = 0; i < 4; ++i)
      gload16(pb + (size_t)i * 32 * ldb + k0, lb0 + i * 2048);
    __syncthreads();                 // drains vmcnt (lds) + barrier
    #pragma unroll
    for (int kk = 0; kk < 2; ++kk) {
      short8 af[4], bfr[4];
      #pragma unroll
      for (int mi = 0; mi < 4; ++mi) {
        int r = (wm << 6) + (mi << 4) + (lane & 15);
        af[mi] = __builtin_bit_cast(short8,
            ((const uint4*)Asm)[r * 8 + ((kk * 4 + (lane >> 4)) ^ (r & 7))]);
      }
      #pragma unroll
      for (int ni = 0; ni < 4; ++ni) {
        int r = (wn << 6) + (ni << 4) + (lane & 15);
        bfr[ni] = __builtin_bit_cast(short8,
            ((const uint4*)Bsm)[r * 8 + ((kk * 4 + (lane >> 4)) ^ (r & 7))]);
      }
      #pragma unroll
      for (int mi = 0; mi < 4; ++mi)
        #pragma unroll
        for (int ni = 0; ni < 4; ++ni)
          acc[mi][ni] = __builtin_amdgcn_mfma_f32_16x16x32_bf16(
              af[mi], bfr[ni], acc[mi][ni], 0, 0, 0);
    }
  }

  #pragma unroll
  for (int mi = 0; mi < 4; ++mi) {
    int rbase = m0 + (wm << 6) + (mi << 4) + ((lane >> 4) << 2);
    #pragma unroll
    for (int ni = 0; ni < 4; ++ni) {
      int col = n0 + (wn << 6) + (ni << 4) + (lane & 15);
      f32x4 v = acc[mi][ni];
      #pragma unroll
      for (int r = 0; r < 4; ++r) {
        size_t idx = ((size_t)bz * 1024 + rbase + r) * 1024 + col;
        if (ADDX) C[idx] = v[r] + X[idx];
        else      C[idx] = v[r];
      }
    }
  }
}

// ---------------- Kernel 4: row softmax, P bf16 in place ---------------------
__global__ __launch_bounds__(256) void softmax_rows(float* __restrict__ S)
{
  size_t rowi = blockIdx.x;
  float* srow = S + rowi * 1024;
  int t = threadIdx.x;
  float4 v = ((const float4*)srow)[t];
  float m = fmaxf(fmaxf(v.x, v.y), fmaxf(v.z, v.w));
  #pragma unroll
  for (int off = 32; off > 0; off >>= 1) m = fmaxf(m, __shfl_xor(m, off));
  __shared__ float red[8];
  int wid = t >> 6, lane = t & 63;
  if (lane == 0) red[wid] = m;
  __syncthreads();
  m = fmaxf(fmaxf(red[0], red[1]), fmaxf(red[2], red[3]));
  float e0 = __expf(v.x - m), e1 = __expf(v.y - m);
  float e2 = __expf(v.z - m), e3 = __expf(v.w - m);
  float s = e0 + e1 + e2 + e3;
  #pragma unroll
  for (int off = 32; off > 0; off >>= 1) s += __shfl_xor(s, off);
  if (lane == 0) red[4 + wid] = s;
  __syncthreads();
  s = red[4] + red[5] + red[6] + red[7];
  float inv = 1.0f / s;
  union { ushort h[4]; uint2 q; } pk;
  pk.h[0] = f2bf(e0 * inv); pk.h[1] = f2bf(e1 * inv);
  pk.h[2] = f2bf(e2 * inv); pk.h[3] = f2bf(e3 * inv);
  ((uint2*)srow)[t] = pk.q;
}

// ---------------- Launch -----------------------------------------------------
extern "C" void kernel_launch(void* const* d_in, const int* in_sizes, int n_in,
                              void* d_out, int out_size, void* d_ws, size_t ws_size,
                              hipStream_t stream) {
  const float* x  = (const float*)d_in[0];
  const float* Wq = (const float*)d_in[1];
  const float* bq = (const float*)d_in[2];
  const float* Wk = (const float*)d_in[3];
  const float* bk = (const float*)d_in[4];
  const float* Wv = (const float*)d_in[5];
  const float* bv = (const float*)d_in[6];
  float* out = (float*)d_out;

  char* wsb = (char*)d_ws;
  ushort* Qt2 = (ushort*)wsb;                          // 12,582,912 B
  ushort* Kt2 = (ushort*)(wsb + 12582912);             // 12,582,912 B
  ushort* Vt  = (ushort*)(wsb + 25165824);             // 33,554,432 B
  float*  S   = (float*)(wsb + 58720256);              // 67,108,864 B (P in place)
  ushort* Vnat = (ushort*)S;                           // first 32MB of S (dead before gemm1)

  proj5<<<2048, 320, 0, stream>>>(x, Wq, bq, Wk, bk, Wv, bv, Qt2, Kt2, Vnat);
  transpose_v<<<dim3(256, 16), 256, 0, stream>>>(Vnat, Vt);
  gemm_nt<384, false><<<1024, 256, 0, stream>>>(Qt2, 384, Kt2, 384, S, nullptr);
  softmax_rows<<<16384, 256, 0, stream>>>(S);
  gemm_nt<1024, true><<<1024, 256, 0, stream>>>((const ushort*)S, 2048, Vt, 1024, out, x);
}

// Round 9
// 170.859 us; speedup vs baseline: 1.5375x; 1.5375x over previous
//
#include <hip/hip_runtime.h>
#include <stdint.h>

typedef uint32_t u32;
typedef __attribute__((ext_vector_type(4))) float f32x4;
typedef __attribute__((ext_vector_type(8))) short short8;

#define NBATCH 16
#define NPIX   16384      // H*W
#define NPB    1048576    // per-batch flat elems (C*H*W = 1024*1024)

__device__ __forceinline__ ushort f2bf(float f) {
  u32 b = __builtin_bit_cast(u32, f);
  return (ushort)((b + 0x7FFFu + ((b >> 16) & 1u)) >> 16);
}
__device__ __forceinline__ float bf2f(ushort h) {
  return __builtin_bit_cast(float, (u32)h << 16);
}

// async global->LDS, 16B per lane. LDS dest must be wave-uniform base;
// HW scatters lane i at base + i*16.
__device__ __forceinline__ void gload16(const ushort* g, ushort* l) {
  __builtin_amdgcn_global_load_lds(
      (const __attribute__((address_space(1))) u32*)(const void*)g,
      (__attribute__((address_space(3))) u32*)(void*)l,
      16, 0, 0);
}

// ---------------- Kernel 0: pack weights -------------------------------------
// wp[cb][o][j] = W[o][cb*4+j], o in [0,80): 0..7=q, 8..15=k, 16..79=v.
__global__ void prep_w(const float* __restrict__ Wq, const float* __restrict__ bq,
                       const float* __restrict__ Wk, const float* __restrict__ bk,
                       const float* __restrict__ Wv, const float* __restrict__ bv,
                       float* __restrict__ wp, float* __restrict__ bpk)
{
  int gid = blockIdx.x * 256 + threadIdx.x;
  if (gid < 5120) {
    int cb = gid / 320;
    int r = gid - cb * 320;
    int o = r >> 2, j = r & 3;
    int c = cb * 4 + j;
    float v = (o < 8) ? Wq[o * 64 + c]
            : (o < 16) ? Wk[(o - 8) * 64 + c]
                       : Wv[(o - 16) * 64 + c];
    wp[gid] = v;
  } else if (gid < 5200) {
    int o = gid - 5120;
    bpk[o] = (o < 8) ? bq[o] : (o < 16 ? bk[o - 8] : bv[o - 16]);
  }
}

// ---------------- Kernel 1: projections, 64-px LDS tile ----------------------
// R7 proj4 structure (known-good), tile halved 128->64 px: LDS 16KB -> ~6
// blocks/CU resident (vs 2.3), so staging (HBM) and weight s_loads (SMEM)
// of one block overlap compute of others. Block = 320 threads (5 waves),
// lane owns ONE pixel; wave w = output group (w0: q+k split-bf16, w1..4:
// 16 V channels each). Weights via uniform s_loads from prepacked wp.
__global__ __launch_bounds__(320) void proj6(
    const float* __restrict__ x, const float* __restrict__ wp,
    const float* __restrict__ bpk,
    ushort* __restrict__ Qt2, ushort* __restrict__ Kt2,
    ushort* __restrict__ Vnat)
{
  __shared__ float xs[64][64];
  int t = threadIdx.x;
  int tile = blockIdx.x;           // 4096 = 16 batches x 256 tiles
  int b = tile >> 8;
  int p0 = (tile & 255) << 6;
  const float* xb = x + (size_t)b * NPB;

  for (int i = t; i < 4096; i += 320) {
    int ch = i >> 6, px = i & 63;
    xs[ch][px] = xb[(size_t)ch * NPIX + p0 + px];
  }
  __syncthreads();

  int w = t >> 6, j = t & 63;
  int ob = __builtin_amdgcn_readfirstlane(w * 16);

  float acc[16];
  #pragma unroll
  for (int o = 0; o < 16; ++o) acc[o] = bpk[ob + o];

  const f32x4* wp4 = (const f32x4*)wp;
  for (int cb = 0; cb < 16; ++cb) {
    float x0 = xs[cb * 4 + 0][j];
    float x1 = xs[cb * 4 + 1][j];
    float x2 = xs[cb * 4 + 2][j];
    float x3 = xs[cb * 4 + 3][j];
    #pragma unroll
    for (int o = 0; o < 16; ++o) {
      f32x4 wv = wp4[cb * 80 + ob + o];
      acc[o] += wv[0] * x0 + wv[1] * x1 + wv[2] * x2 + wv[3] * x3;
    }
  }

  if (w == 0) {
    // Q/K split bf16: Q = [qh][ql][qh], K = [kh][kh][kl] so that
    // dot = qh*kh + ql*kh + qh*kl (drops only ~2e-4 ql*kl term).
    int p = p0 + j;
    int l = p & 1023, tc = p >> 10;
    union { ushort s[8]; uint4 q; } qh, ql, kh, kl;
    #pragma unroll
    for (int o = 0; o < 8; ++o) {
      float qv = acc[o];
      ushort h = f2bf(qv);
      qh.s[o] = h; ql.s[o] = f2bf(qv - bf2f(h));
      float kv = acc[8 + o];
      h = f2bf(kv);
      kh.s[o] = h; kl.s[o] = f2bf(kv - bf2f(h));
    }
    ushort* qrow = Qt2 + ((size_t)b * 1024 + l) * 384 + tc * 8;
    *(uint4*)qrow         = qh.q;
    *(uint4*)(qrow + 128) = ql.q;
    *(uint4*)(qrow + 256) = qh.q;
    ushort* krow = Kt2 + ((size_t)b * 1024 + l) * 384 + tc * 8;
    *(uint4*)krow         = kh.q;
    *(uint4*)(krow + 128) = kh.q;
    *(uint4*)(krow + 256) = kl.q;
  } else {
    int cbase = ob - 16;
    ushort* vb = Vnat + (size_t)b * NPB + (size_t)cbase * NPIX + p0 + j;
    #pragma unroll
    for (int c = 0; c < 16; ++c)
      vb[(size_t)c * NPIX] = f2bf(acc[c]);
  }
}

// ---------------- Kernel 2: V transpose --------------------------------------
// Vt[a][p'] = Vnat_flat[p'*1024 + a]
__global__ __launch_bounds__(256) void transpose_v(
    const ushort* __restrict__ Vnat, ushort* __restrict__ Vt)
{
  __shared__ ushort tile[64][80];
  int b = blockIdx.y;
  int p0 = (blockIdx.x >> 4) << 6;
  int c0 = (blockIdx.x & 15) << 6;
  int t = threadIdx.x;
  int pr = t >> 2, ch = t & 3;
  int p = p0 + pr;
  const ushort* src = Vnat + (size_t)b * NPB + (size_t)(p >> 4) * NPIX +
                      (size_t)(p & 15) * 1024 + c0 + ch * 16;
  uint4 v0 = ((const uint4*)src)[0];
  uint4 v1 = ((const uint4*)src)[1];
  *(uint4*)&tile[pr][ch * 16] = v0;
  *(uint4*)&tile[pr][ch * 16 + 8] = v1;
  __syncthreads();
  int cl = t >> 2, pch = t & 3;
  union { ushort s[16]; uint4 q[2]; } outv;
  #pragma unroll
  for (int j = 0; j < 16; ++j) outv.s[j] = tile[pch * 16 + j][cl];
  ushort* dst = Vt + (size_t)b * NPB + (size_t)(c0 + cl) * 1024 + p0 + pch * 16;
  ((uint4*)dst)[0] = outv.q[0];
  ((uint4*)dst)[1] = outv.q[1];
}

// ---------------- Kernels 3/5: NT bf16 MFMA GEMM (m97 + src-side swizzle) ----
// C[i][j] = sum_k A[i][k]*B[j][k]; per-batch 1024x1024, tile 128x128, BK=64.
// global_load_lds width-16 staging, LINEAR LDS dest, global SOURCE chunk
// XOR-pre-swizzled (chunk' = chunk ^ (row&7)) with the same XOR on fragment
// reads -> bank-conflict-free. XCD-chunked 1D grid (2 batches per XCD).
template<int KTOT, bool ADDX>
__global__ __launch_bounds__(256) void gemm_nt(
    const ushort* __restrict__ A, int lda,
    const ushort* __restrict__ B, int ldb,
    float* __restrict__ C, const float* __restrict__ X)
{
  __shared__ ushort Asm[128 * 64];
  __shared__ ushort Bsm[128 * 64];
  int t = threadIdx.x;

  // bijective XCD-chunk remap (1024 blocks, 8 XCDs, 128 each = 2 batches)
  int g = blockIdx.x;
  int lin = (g & 7) * 128 + (g >> 3);
  int bz = lin >> 6;
  int by = (lin >> 3) & 7;
  int bx = lin & 7;
  int m0 = by << 7, n0 = bx << 7;

  const ushort* Ab = A + (size_t)bz * 1024 * lda;
  const ushort* Bb = B + (size_t)bz * 1024 * ldb;
  int wid = t >> 6, lane = t & 63;
  int wm = wid >> 1, wn = wid & 1;

  int swc = (t & 7) ^ ((t >> 3) & 7);
  const ushort* pa = Ab + (size_t)(m0 + (t >> 3)) * lda + swc * 8;
  const ushort* pb = Bb + (size_t)(n0 + (t >> 3)) * ldb + swc * 8;
  ushort* la0 = Asm + (size_t)(t >> 6) * 512;   // wave base, elems (1024 B)
  ushort* lb0 = Bsm + (size_t)(t >> 6) * 512;

  f32x4 acc[4][4] = {};

  for (int k0 = 0; k0 < KTOT; k0 += 64) {
    __syncthreads();                 // previous compute done before overwrite
    #pragma unroll
    for (int i = 0; i < 4; ++i)
      gload16(pa + (size_t)i * 32 * lda + k0, la0 + i * 2048);
    #pragma unroll
    for (int i = 0; i < 4; ++i)
      gload16(pb + (size_t)i * 32 * ldb + k0, lb0 + i * 2048);
    __syncthreads();                 // drains vmcnt (lds) + barrier
    #pragma unroll
    for (int kk = 0; kk < 2; ++kk) {
      short8 af[4], bfr[4];
      #pragma unroll
      for (int mi = 0; mi < 4; ++mi) {
        int r = (wm << 6) + (mi << 4) + (lane & 15);
        af[mi] = __builtin_bit_cast(short8,
            ((const uint4*)Asm)[r * 8 + ((kk * 4 + (lane >> 4)) ^ (r & 7))]);
      }
      #pragma unroll
      for (int ni = 0; ni < 4; ++ni) {
        int r = (wn << 6) + (ni << 4) + (lane & 15);
        bfr[ni] = __builtin_bit_cast(short8,
            ((const uint4*)Bsm)[r * 8 + ((kk * 4 + (lane >> 4)) ^ (r & 7))]);
      }
      #pragma unroll
      for (int mi = 0; mi < 4; ++mi)
        #pragma unroll
        for (int ni = 0; ni < 4; ++ni)
          acc[mi][ni] = __builtin_amdgcn_mfma_f32_16x16x32_bf16(
              af[mi], bfr[ni], acc[mi][ni], 0, 0, 0);
    }
  }

  #pragma unroll
  for (int mi = 0; mi < 4; ++mi) {
    int rbase = m0 + (wm << 6) + (mi << 4) + ((lane >> 4) << 2);
    #pragma unroll
    for (int ni = 0; ni < 4; ++ni) {
      int col = n0 + (wn << 6) + (ni << 4) + (lane & 15);
      f32x4 v = acc[mi][ni];
      #pragma unroll
      for (int r = 0; r < 4; ++r) {
        size_t idx = ((size_t)bz * 1024 + rbase + r) * 1024 + col;
        if (ADDX) C[idx] = v[r] + X[idx];
        else      C[idx] = v[r];
      }
    }
  }
}

// ---------------- Kernel 4: row softmax, P bf16 in place ---------------------
__global__ __launch_bounds__(256) void softmax_rows(float* __restrict__ S)
{
  size_t rowi = blockIdx.x;
  float* srow = S + rowi * 1024;
  int t = threadIdx.x;
  float4 v = ((const float4*)srow)[t];
  float m = fmaxf(fmaxf(v.x, v.y), fmaxf(v.z, v.w));
  #pragma unroll
  for (int off = 32; off > 0; off >>= 1) m = fmaxf(m, __shfl_xor(m, off));
  __shared__ float red[8];
  int wid = t >> 6, lane = t & 63;
  if (lane == 0) red[wid] = m;
  __syncthreads();
  m = fmaxf(fmaxf(red[0], red[1]), fmaxf(red[2], red[3]));
  float e0 = __expf(v.x - m), e1 = __expf(v.y - m);
  float e2 = __expf(v.z - m), e3 = __expf(v.w - m);
  float s = e0 + e1 + e2 + e3;
  #pragma unroll
  for (int off = 32; off > 0; off >>= 1) s += __shfl_xor(s, off);
  if (lane == 0) red[4 + wid] = s;
  __syncthreads();
  s = red[4] + red[5] + red[6] + red[7];
  float inv = 1.0f / s;
  union { ushort h[4]; uint2 q; } pk;
  pk.h[0] = f2bf(e0 * inv); pk.h[1] = f2bf(e1 * inv);
  pk.h[2] = f2bf(e2 * inv); pk.h[3] = f2bf(e3 * inv);
  ((uint2*)srow)[t] = pk.q;
}

// ---------------- Launch -----------------------------------------------------
extern "C" void kernel_launch(void* const* d_in, const int* in_sizes, int n_in,
                              void* d_out, int out_size, void* d_ws, size_t ws_size,
                              hipStream_t stream) {
  const float* x  = (const float*)d_in[0];
  const float* Wq = (const float*)d_in[1];
  const float* bq = (const float*)d_in[2];
  const float* Wk = (const float*)d_in[3];
  const float* bk = (const float*)d_in[4];
  const float* Wv = (const float*)d_in[5];
  const float* bv = (const float*)d_in[6];
  float* out = (float*)d_out;

  char* wsb = (char*)d_ws;
  ushort* Qt2 = (ushort*)wsb;                          // 12,582,912 B
  ushort* Kt2 = (ushort*)(wsb + 12582912);             // 12,582,912 B
  ushort* Vt  = (ushort*)(wsb + 25165824);             // 33,554,432 B
  float*  S   = (float*)(wsb + 58720256);              // 67,108,864 B (P in place)
  ushort* Vnat = (ushort*)S;                           // first 32MB of S (dead before gemm1)
  float*  wp  = (float*)(wsb + 92274688);              // after Vnat, still inside S
  float*  bpk = wp + 5120;

  prep_w<<<21, 256, 0, stream>>>(Wq, bq, Wk, bk, Wv, bv, wp, bpk);
  proj6<<<4096, 320, 0, stream>>>(x, wp, bpk, Qt2, Kt2, Vnat);
  transpose_v<<<dim3(256, 16), 256, 0, stream>>>(Vnat, Vt);
  gemm_nt<384, false><<<1024, 256, 0, stream>>>(Qt2, 384, Kt2, 384, S, nullptr);
  softmax_rows<<<16384, 256, 0, stream>>>(S);
  gemm_nt<1024, true><<<1024, 256, 0, stream>>>((const ushort*)S, 2048, Vt, 1024, out, x);
}

// Round 10
// 167.130 us; speedup vs baseline: 1.5718x; 1.0223x over previous
//
#include <hip/hip_runtime.h>
#include <stdint.h>

typedef uint32_t u32;
typedef __attribute__((ext_vector_type(4))) float f32x4;
typedef __attribute__((ext_vector_type(8))) short short8;

#define NBATCH 16
#define NPIX   16384      // H*W
#define NPB    1048576    // per-batch flat elems (C*H*W = 1024*1024)

__device__ __forceinline__ ushort f2bf(float f) {
  u32 b = __builtin_bit_cast(u32, f);
  return (ushort)((b + 0x7FFFu + ((b >> 16) & 1u)) >> 16);
}
__device__ __forceinline__ float bf2f(ushort h) {
  return __builtin_bit_cast(float, (u32)h << 16);
}

// async global->LDS, 16B per lane. LDS dest must be wave-uniform base;
// HW scatters lane i at base + i*16.
__device__ __forceinline__ void gload16(const ushort* g, ushort* l) {
  __builtin_amdgcn_global_load_lds(
      (const __attribute__((address_space(1))) u32*)(const void*)g,
      (__attribute__((address_space(3))) u32*)(void*)l,
      16, 0, 0);
}

// ---------------- Kernel 0: pack weights -------------------------------------
// wp[cb][o][j] = W[o][cb*4+j], o in [0,80): 0..7=q, 8..15=k, 16..79=v.
__global__ void prep_w(const float* __restrict__ Wq, const float* __restrict__ bq,
                       const float* __restrict__ Wk, const float* __restrict__ bk,
                       const float* __restrict__ Wv, const float* __restrict__ bv,
                       float* __restrict__ wp, float* __restrict__ bpk)
{
  int gid = blockIdx.x * 256 + threadIdx.x;
  if (gid < 5120) {
    int cb = gid / 320;
    int r = gid - cb * 320;
    int o = r >> 2, j = r & 3;
    int c = cb * 4 + j;
    float v = (o < 8) ? Wq[o * 64 + c]
            : (o < 16) ? Wk[(o - 8) * 64 + c]
                       : Wv[(o - 16) * 64 + c];
    wp[gid] = v;
  } else if (gid < 5200) {
    int o = gid - 5120;
    bpk[o] = (o < 8) ? bq[o] : (o < 16 ? bk[o - 8] : bv[o - 16]);
  }
}

// ---------------- Kernel 1: projections, no-LDS XCD-grouped ------------------
// 1280 blocks = 256 tiles (1024 px) x 5 groups, decoded i = q*40 + g*8 + r,
// tile = q*8 + r. All 5 group-blocks of a tile land on XCD r (i mod 8 == r)
// and are dispatch-adjacent -> x tile (256KB) fetched from HBM once per XCD,
// re-read from that XCD's L2. No barriers, no LDS. Lane owns 4 px
// {2t,2t+1,512+2t,512+2t+1}: float2 loads, 256 FMA/cb (2x proj4's
// s_load-latency amortization). g==0: q+k split-bf16; g>=1: 16 V channels.
__global__ __launch_bounds__(256) void proj7(
    const float* __restrict__ x, const float* __restrict__ wp,
    const float* __restrict__ bpk,
    ushort* __restrict__ Qt2, ushort* __restrict__ Kt2,
    ushort* __restrict__ Vnat)
{
  int t = threadIdx.x;
  int bi = blockIdx.x;
  int q = bi / 40, rem = bi - q * 40;
  int g = rem >> 3, r = rem & 7;
  int tile = q * 8 + r;            // [0,256)
  int b = tile >> 4;
  int ptile0 = (tile & 15) << 10;
  int tc = tile & 15;
  int ob = (g == 0) ? 0 : 16 * g;
  const float* xb = x + (size_t)b * NPB + ptile0 + 2 * t;

  float acc[16][4];
  #pragma unroll
  for (int o = 0; o < 16; ++o) {
    float bb = bpk[ob + o];
    acc[o][0] = bb; acc[o][1] = bb; acc[o][2] = bb; acc[o][3] = bb;
  }

  const f32x4* wp4 = (const f32x4*)wp;
  for (int cb = 0; cb < 16; ++cb) {
    float2 xv[4][2];
    #pragma unroll
    for (int ch = 0; ch < 4; ++ch)
      #pragma unroll
      for (int k = 0; k < 2; ++k)
        xv[ch][k] = *(const float2*)&xb[(size_t)(cb * 4 + ch) * NPIX + k * 512];
    #pragma unroll
    for (int o = 0; o < 16; ++o) {
      f32x4 wv = wp4[cb * 80 + ob + o];
      #pragma unroll
      for (int k = 0; k < 2; ++k) {
        acc[o][k * 2 + 0] += wv[0] * xv[0][k].x + wv[1] * xv[1][k].x
                           + wv[2] * xv[2][k].x + wv[3] * xv[3][k].x;
        acc[o][k * 2 + 1] += wv[0] * xv[0][k].y + wv[1] * xv[1][k].y
                           + wv[2] * xv[2][k].y + wv[3] * xv[3][k].y;
      }
    }
  }

  if (g == 0) {
    // Q/K split bf16: Q = [qh][ql][qh], K = [kh][kh][kl] so that
    // dot = qh*kh + ql*kh + qh*kl (drops only ~2e-4 ql*kl term).
    #pragma unroll
    for (int k = 0; k < 2; ++k) {
      #pragma unroll
      for (int ii = 0; ii < 2; ++ii) {
        int l = k * 512 + 2 * t + ii;
        union { ushort s[8]; uint4 v; } qh, ql, kh, kl;
        #pragma unroll
        for (int o = 0; o < 8; ++o) {
          float qv = acc[o][k * 2 + ii];
          ushort h = f2bf(qv);
          qh.s[o] = h; ql.s[o] = f2bf(qv - bf2f(h));
          float kv = acc[8 + o][k * 2 + ii];
          h = f2bf(kv);
          kh.s[o] = h; kl.s[o] = f2bf(kv - bf2f(h));
        }
        ushort* qrow = Qt2 + ((size_t)b * 1024 + l) * 384 + tc * 8;
        *(uint4*)qrow         = qh.v;
        *(uint4*)(qrow + 128) = ql.v;
        *(uint4*)(qrow + 256) = qh.v;
        ushort* krow = Kt2 + ((size_t)b * 1024 + l) * 384 + tc * 8;
        *(uint4*)krow         = kh.v;
        *(uint4*)(krow + 128) = kh.v;
        *(uint4*)(krow + 256) = kl.v;
      }
    }
  } else {
    int cbase = ob - 16;
    ushort* vb = Vnat + (size_t)b * NPB + (size_t)cbase * NPIX + ptile0 + 2 * t;
    #pragma unroll
    for (int c = 0; c < 16; ++c) {
      #pragma unroll
      for (int k = 0; k < 2; ++k) {
        u32 pk2 = (u32)f2bf(acc[c][k * 2]) | ((u32)f2bf(acc[c][k * 2 + 1]) << 16);
        *(u32*)(vb + (size_t)c * NPIX + k * 512) = pk2;
      }
    }
  }
}

// ---------------- Kernel 2: V transpose --------------------------------------
// Vt[a][p'] = Vnat_flat[p'*1024 + a]
__global__ __launch_bounds__(256) void transpose_v(
    const ushort* __restrict__ Vnat, ushort* __restrict__ Vt)
{
  __shared__ ushort tile[64][80];
  int b = blockIdx.y;
  int p0 = (blockIdx.x >> 4) << 6;
  int c0 = (blockIdx.x & 15) << 6;
  int t = threadIdx.x;
  int pr = t >> 2, ch = t & 3;
  int p = p0 + pr;
  const ushort* src = Vnat + (size_t)b * NPB + (size_t)(p >> 4) * NPIX +
                      (size_t)(p & 15) * 1024 + c0 + ch * 16;
  uint4 v0 = ((const uint4*)src)[0];
  uint4 v1 = ((const uint4*)src)[1];
  *(uint4*)&tile[pr][ch * 16] = v0;
  *(uint4*)&tile[pr][ch * 16 + 8] = v1;
  __syncthreads();
  int cl = t >> 2, pch = t & 3;
  union { ushort s[16]; uint4 q[2]; } outv;
  #pragma unroll
  for (int j = 0; j < 16; ++j) outv.s[j] = tile[pch * 16 + j][cl];
  ushort* dst = Vt + (size_t)b * NPB + (size_t)(c0 + cl) * 1024 + p0 + pch * 16;
  ((uint4*)dst)[0] = outv.q[0];
  ((uint4*)dst)[1] = outv.q[1];
}

// ---------------- Kernels 3/5: NT bf16 MFMA GEMM (m97 + src-side swizzle) ----
// C[i][j] = sum_k A[i][k]*B[j][k]; per-batch 1024x1024, tile 128x128, BK=64.
// global_load_lds width-16 staging, LINEAR LDS dest, global SOURCE chunk
// XOR-pre-swizzled (chunk' = chunk ^ (row&7)) with the same XOR on fragment
// reads -> bank-conflict-free. XCD-chunked 1D grid (2 batches per XCD).
template<int KTOT, bool ADDX>
__global__ __launch_bounds__(256) void gemm_nt(
    const ushort* __restrict__ A, int lda,
    const ushort* __restrict__ B, int ldb,
    float* __restrict__ C, const float* __restrict__ X)
{
  __shared__ ushort Asm[128 * 64];
  __shared__ ushort Bsm[128 * 64];
  int t = threadIdx.x;

  // bijective XCD-chunk remap (1024 blocks, 8 XCDs, 128 each = 2 batches)
  int g = blockIdx.x;
  int lin = (g & 7) * 128 + (g >> 3);
  int bz = lin >> 6;
  int by = (lin >> 3) & 7;
  int bx = lin & 7;
  int m0 = by << 7, n0 = bx << 7;

  const ushort* Ab = A + (size_t)bz * 1024 * lda;
  const ushort* Bb = B + (size_t)bz * 1024 * ldb;
  int wid = t >> 6, lane = t & 63;
  int wm = wid >> 1, wn = wid & 1;

  int swc = (t & 7) ^ ((t >> 3) & 7);
  const ushort* pa = Ab + (size_t)(m0 + (t >> 3)) * lda + swc * 8;
  const ushort* pb = Bb + (size_t)(n0 + (t >> 3)) * ldb + swc * 8;
  ushort* la0 = Asm + (size_t)(t >> 6) * 512;   // wave base, elems (1024 B)
  ushort* lb0 = Bsm + (size_t)(t >> 6) * 512;

  f32x4 acc[4][4] = {};

  for (int k0 = 0; k0 < KTOT; k0 += 64) {
    __syncthreads();                 // previous compute done before overwrite
    #pragma unroll
    for (int i = 0; i < 4; ++i)
      gload16(pa + (size_t)i * 32 * lda + k0, la0 + i * 2048);
    #pragma unroll
    for (int i = 0; i < 4; ++i)
      gload16(pb + (size_t)i * 32 * ldb + k0, lb0 + i * 2048);
    __syncthreads();                 // drains vmcnt (lds) + barrier
    #pragma unroll
    for (int kk = 0; kk < 2; ++kk) {
      short8 af[4], bfr[4];
      #pragma unroll
      for (int mi = 0; mi < 4; ++mi) {
        int rr = (wm << 6) + (mi << 4) + (lane & 15);
        af[mi] = __builtin_bit_cast(short8,
            ((const uint4*)Asm)[rr * 8 + ((kk * 4 + (lane >> 4)) ^ (rr & 7))]);
      }
      #pragma unroll
      for (int ni = 0; ni < 4; ++ni) {
        int rr = (wn << 6) + (ni << 4) + (lane & 15);
        bfr[ni] = __builtin_bit_cast(short8,
            ((const uint4*)Bsm)[rr * 8 + ((kk * 4 + (lane >> 4)) ^ (rr & 7))]);
      }
      #pragma unroll
      for (int mi = 0; mi < 4; ++mi)
        #pragma unroll
        for (int ni = 0; ni < 4; ++ni)
          acc[mi][ni] = __builtin_amdgcn_mfma_f32_16x16x32_bf16(
              af[mi], bfr[ni], acc[mi][ni], 0, 0, 0);
    }
  }

  #pragma unroll
  for (int mi = 0; mi < 4; ++mi) {
    int rbase = m0 + (wm << 6) + (mi << 4) + ((lane >> 4) << 2);
    #pragma unroll
    for (int ni = 0; ni < 4; ++ni) {
      int col = n0 + (wn << 6) + (ni << 4) + (lane & 15);
      f32x4 v = acc[mi][ni];
      #pragma unroll
      for (int rr = 0; rr < 4; ++rr) {
        size_t idx = ((size_t)bz * 1024 + rbase + rr) * 1024 + col;
        if (ADDX) C[idx] = v[rr] + X[idx];
        else      C[idx] = v[rr];
      }
    }
  }
}

// ---------------- Kernel 4: row softmax, P bf16 in place ---------------------
__global__ __launch_bounds__(256) void softmax_rows(float* __restrict__ S)
{
  size_t rowi = blockIdx.x;
  float* srow = S + rowi * 1024;
  int t = threadIdx.x;
  float4 v = ((const float4*)srow)[t];
  float m = fmaxf(fmaxf(v.x, v.y), fmaxf(v.z, v.w));
  #pragma unroll
  for (int off = 32; off > 0; off >>= 1) m = fmaxf(m, __shfl_xor(m, off));
  __shared__ float red[8];
  int wid = t >> 6, lane = t & 63;
  if (lane == 0) red[wid] = m;
  __syncthreads();
  m = fmaxf(fmaxf(red[0], red[1]), fmaxf(red[2], red[3]));
  float e0 = __expf(v.x - m), e1 = __expf(v.y - m);
  float e2 = __expf(v.z - m), e3 = __expf(v.w - m);
  float s = e0 + e1 + e2 + e3;
  #pragma unroll
  for (int off = 32; off > 0; off >>= 1) s += __shfl_xor(s, off);
  if (lane == 0) red[4 + wid] = s;
  __syncthreads();
  s = red[4] + red[5] + red[6] + red[7];
  float inv = 1.0f / s;
  union { ushort h[4]; uint2 q; } pk;
  pk.h[0] = f2bf(e0 * inv); pk.h[1] = f2bf(e1 * inv);
  pk.h[2] = f2bf(e2 * inv); pk.h[3] = f2bf(e3 * inv);
  ((uint2*)srow)[t] = pk.q;
}

// ---------------- Launch -----------------------------------------------------
extern "C" void kernel_launch(void* const* d_in, const int* in_sizes, int n_in,
                              void* d_out, int out_size, void* d_ws, size_t ws_size,
                              hipStream_t stream) {
  const float* x  = (const float*)d_in[0];
  const float* Wq = (const float*)d_in[1];
  const float* bq = (const float*)d_in[2];
  const float* Wk = (const float*)d_in[3];
  const float* bk = (const float*)d_in[4];
  const float* Wv = (const float*)d_in[5];
  const float* bv = (const float*)d_in[6];
  float* out = (float*)d_out;

  char* wsb = (char*)d_ws;
  ushort* Qt2 = (ushort*)wsb;                          // 12,582,912 B
  ushort* Kt2 = (ushort*)(wsb + 12582912);             // 12,582,912 B
  ushort* Vt  = (ushort*)(wsb + 25165824);             // 33,554,432 B
  float*  S   = (float*)(wsb + 58720256);              // 67,108,864 B (P in place)
  ushort* Vnat = (ushort*)S;                           // first 32MB of S (dead before gemm1)
  float*  wp  = (float*)(wsb + 92274688);              // after Vnat, still inside S
  float*  bpk = wp + 5120;

  prep_w<<<21, 256, 0, stream>>>(Wq, bq, Wk, bk, Wv, bv, wp, bpk);
  proj7<<<1280, 256, 0, stream>>>(x, wp, bpk, Qt2, Kt2, Vnat);
  transpose_v<<<dim3(256, 16), 256, 0, stream>>>(Vnat, Vt);
  gemm_nt<384, false><<<1024, 256, 0, stream>>>(Qt2, 384, Kt2, 384, S, nullptr);
  softmax_rows<<<16384, 256, 0, stream>>>(S);
  gemm_nt<1024, true><<<1024, 256, 0, stream>>>((const ushort*)S, 2048, Vt, 1024, out, x);
}

// Round 11
// 156.097 us; speedup vs baseline: 1.6829x; 1.0707x over previous
//
#include <hip/hip_runtime.h>
#include <stdint.h>

typedef uint32_t u32;
typedef __attribute__((ext_vector_type(4))) float f32x4;
typedef __attribute__((ext_vector_type(8))) short short8;

#define NBATCH 16
#define NPIX   16384      // H*W
#define NPB    1048576    // per-batch flat elems (C*H*W = 1024*1024)

__device__ __forceinline__ ushort f2bf(float f) {
  u32 b = __builtin_bit_cast(u32, f);
  return (ushort)((b + 0x7FFFu + ((b >> 16) & 1u)) >> 16);
}
__device__ __forceinline__ float bf2f(ushort h) {
  return __builtin_bit_cast(float, (u32)h << 16);
}

// async global->LDS, 16B per lane. LDS dest must be wave-uniform base;
// HW scatters lane i at base + i*16.
__device__ __forceinline__ void gload16(const ushort* g, ushort* l) {
  __builtin_amdgcn_global_load_lds(
      (const __attribute__((address_space(1))) u32*)(const void*)g,
      (__attribute__((address_space(3))) u32*)(void*)l,
      16, 0, 0);
}

// ---------------- Kernel 0: pack weights -------------------------------------
// wp2[ch][o] = W[o][ch]  (80 floats per ch row; 80%16==0 so each wave's
// 16-dword group is 64B-aligned -> s_load_dwordx16). bpk[o] = bias.
__global__ void prep_w(const float* __restrict__ Wq, const float* __restrict__ bq,
                       const float* __restrict__ Wk, const float* __restrict__ bk,
                       const float* __restrict__ Wv, const float* __restrict__ bv,
                       float* __restrict__ wp2, float* __restrict__ bpk)
{
  int gid = blockIdx.x * 256 + threadIdx.x;
  if (gid < 5120) {
    int ch = gid / 80;
    int o = gid - ch * 80;
    float v = (o < 8) ? Wq[o * 64 + ch]
            : (o < 16) ? Wk[(o - 8) * 64 + ch]
                       : Wv[(o - 16) * 64 + ch];
    wp2[gid] = v;
  } else if (gid < 5200) {
    int o = gid - 5120;
    bpk[o] = (o < 8) ? bq[o] : (o < 16 ? bk[o - 8] : bv[o - 16]);
  }
}

// ---------------- Kernel 1: FUSED projections + transposes -------------------
// Key insight: Qt2, Kt2 and Vt rows are ALL indexed by l = p&1023, with
// (channel, tc=p>>10) as columns. Block owns (batch b, 16-l chunk) across all
// 16 tc strips = 256 pixels. 5 waves x 64 lanes; wave w computes out-group w
// (w0: 8q+8k, w1..4: 16 V ch). Lane = (tc = j>>2, dl = (j&3)*4 .. +4): one
// float4 x load per ch; weights = 16 contiguous uniform floats per ch
// (SGPR double-bufferable). Epilogue: stage q/k fp32 + v bf16 in LDS, then
// 256 threads write Qt2/Kt2 (verified split-bf16 packing) and Vt rows with
// fully-coalesced uint4 stores. transpose_v kernel ELIMINATED.
__global__ __launch_bounds__(320) void proj8(
    const float* __restrict__ x, const float* __restrict__ wp2,
    const float* __restrict__ bpk,
    ushort* __restrict__ Qt2, ushort* __restrict__ Kt2,
    ushort* __restrict__ Vt)
{
  __shared__ float  qkl[16][260];   // [o][px=tc*16+dl], pad 4
  __shared__ ushort vl[64][264];    // [c][px], pad 8 (stride 132 u32 -> 2-way)
  int t = threadIdx.x;
  int b = blockIdx.x >> 6;
  int l0 = (blockIdx.x & 63) << 4;
  int w = t >> 6, j = t & 63;
  int tc = j >> 2, dlg = (j & 3) << 2;
  int ob = __builtin_amdgcn_readfirstlane(w * 16);
  const float* xb = x + (size_t)b * NPB + (size_t)tc * 1024 + l0 + dlg;

  float acc[16][4];
  #pragma unroll
  for (int o = 0; o < 16; ++o) {
    float bb = bpk[ob + o];
    acc[o][0] = bb; acc[o][1] = bb; acc[o][2] = bb; acc[o][3] = bb;
  }

  for (int ch = 0; ch < 64; ++ch) {
    f32x4 xv = *(const f32x4*)(xb + (size_t)ch * NPIX);
    const float* wr = wp2 + ch * 80 + ob;   // uniform, 16 contiguous dwords
    #pragma unroll
    for (int o = 0; o < 16; ++o) {
      float wo = wr[o];
      acc[o][0] += wo * xv[0];
      acc[o][1] += wo * xv[1];
      acc[o][2] += wo * xv[2];
      acc[o][3] += wo * xv[3];
    }
  }

  if (w == 0) {
    #pragma unroll
    for (int o = 0; o < 16; ++o)
      #pragma unroll
      for (int i = 0; i < 4; ++i)
        qkl[o][tc * 16 + dlg + i] = acc[o][i];
  } else {
    int cb = ob - 16;
    #pragma unroll
    for (int o = 0; o < 16; ++o) {
      #pragma unroll
      for (int i = 0; i < 2; ++i) {
        u32 pk2 = (u32)f2bf(acc[o][2 * i]) | ((u32)f2bf(acc[o][2 * i + 1]) << 16);
        *(u32*)&vl[cb + o][tc * 16 + dlg + 2 * i] = pk2;
      }
    }
  }
  __syncthreads();

  if (t < 256) {
    int l = t >> 4, tcc = t & 15;
    size_t lrow = (size_t)b * 1024 + l0 + l;

    // Q/K split bf16 (verified packing): Q = [qh][ql][qh], K = [kh][kh][kl]
    // so dot = qh*kh + ql*kh + qh*kl (drops only ~2e-4 ql*kl term).
    union { ushort s[8]; uint4 v; } qh, ql, kh, kl;
    #pragma unroll
    for (int o = 0; o < 8; ++o) {
      float qv = qkl[o][tcc * 16 + l];
      ushort h = f2bf(qv);
      qh.s[o] = h; ql.s[o] = f2bf(qv - bf2f(h));
      float kv = qkl[8 + o][tcc * 16 + l];
      h = f2bf(kv);
      kh.s[o] = h; kl.s[o] = f2bf(kv - bf2f(h));
    }
    ushort* qrow = Qt2 + lrow * 384 + tcc * 8;
    *(uint4*)qrow         = qh.v;
    *(uint4*)(qrow + 128) = ql.v;
    *(uint4*)(qrow + 256) = qh.v;
    ushort* krow = Kt2 + lrow * 384 + tcc * 8;
    *(uint4*)krow         = kh.v;
    *(uint4*)(krow + 128) = kh.v;
    *(uint4*)(krow + 256) = kl.v;

    // Vt row (l0+l): cols c*16+tt = v[c][p=tt*1024+l0+l] = vl[c][tt*16+l]
    ushort* vrow = Vt + lrow * 1024;
    #pragma unroll
    for (int it = 0; it < 4; ++it) {
      int c2 = (it << 4) + tcc;
      union { ushort s[16]; uint4 q[2]; } ov;
      #pragma unroll
      for (int tt = 0; tt < 16; ++tt)
        ov.s[tt] = vl[c2][tt * 16 + l];
      *(uint4*)(vrow + c2 * 16)     = ov.q[0];
      *(uint4*)(vrow + c2 * 16 + 8) = ov.q[1];
    }
  }
}

// ---------------- Kernels 2/4: NT bf16 MFMA GEMM (m97 + src-side swizzle) ----
// C[i][j] = sum_k A[i][k]*B[j][k]; per-batch 1024x1024, tile 128x128, BK=64.
// global_load_lds width-16 staging, LINEAR LDS dest, global SOURCE chunk
// XOR-pre-swizzled (chunk' = chunk ^ (row&7)) with the same XOR on fragment
// reads -> bank-conflict-free. XCD-chunked 1D grid (2 batches per XCD).
template<int KTOT, bool ADDX>
__global__ __launch_bounds__(256) void gemm_nt(
    const ushort* __restrict__ A, int lda,
    const ushort* __restrict__ B, int ldb,
    float* __restrict__ C, const float* __restrict__ X)
{
  __shared__ ushort Asm[128 * 64];
  __shared__ ushort Bsm[128 * 64];
  int t = threadIdx.x;

  // bijective XCD-chunk remap (1024 blocks, 8 XCDs, 128 each = 2 batches)
  int g = blockIdx.x;
  int lin = (g & 7) * 128 + (g >> 3);
  int bz = lin >> 6;
  int by = (lin >> 3) & 7;
  int bx = lin & 7;
  int m0 = by << 7, n0 = bx << 7;

  const ushort* Ab = A + (size_t)bz * 1024 * lda;
  const ushort* Bb = B + (size_t)bz * 1024 * ldb;
  int wid = t >> 6, lane = t & 63;
  int wm = wid >> 1, wn = wid & 1;

  int swc = (t & 7) ^ ((t >> 3) & 7);
  const ushort* pa = Ab + (size_t)(m0 + (t >> 3)) * lda + swc * 8;
  const ushort* pb = Bb + (size_t)(n0 + (t >> 3)) * ldb + swc * 8;
  ushort* la0 = Asm + (size_t)(t >> 6) * 512;   // wave base, elems (1024 B)
  ushort* lb0 = Bsm + (size_t)(t >> 6) * 512;

  f32x4 acc[4][4] = {};

  for (int k0 = 0; k0 < KTOT; k0 += 64) {
    __syncthreads();                 // previous compute done before overwrite
    #pragma unroll
    for (int i = 0; i < 4; ++i)
      gload16(pa + (size_t)i * 32 * lda + k0, la0 + i * 2048);
    #pragma unroll
    for (int i = 0; i < 4; ++i)
      gload16(pb + (size_t)i * 32 * ldb + k0, lb0 + i * 2048);
    __syncthreads();                 // drains vmcnt (lds) + barrier
    #pragma unroll
    for (int kk = 0; kk < 2; ++kk) {
      short8 af[4], bfr[4];
      #pragma unroll
      for (int mi = 0; mi < 4; ++mi) {
        int rr = (wm << 6) + (mi << 4) + (lane & 15);
        af[mi] = __builtin_bit_cast(short8,
            ((const uint4*)Asm)[rr * 8 + ((kk * 4 + (lane >> 4)) ^ (rr & 7))]);
      }
      #pragma unroll
      for (int ni = 0; ni < 4; ++ni) {
        int rr = (wn << 6) + (ni << 4) + (lane & 15);
        bfr[ni] = __builtin_bit_cast(short8,
            ((const uint4*)Bsm)[rr * 8 + ((kk * 4 + (lane >> 4)) ^ (rr & 7))]);
      }
      #pragma unroll
      for (int mi = 0; mi < 4; ++mi)
        #pragma unroll
        for (int ni = 0; ni < 4; ++ni)
          acc[mi][ni] = __builtin_amdgcn_mfma_f32_16x16x32_bf16(
              af[mi], bfr[ni], acc[mi][ni], 0, 0, 0);
    }
  }

  #pragma unroll
  for (int mi = 0; mi < 4; ++mi) {
    int rbase = m0 + (wm << 6) + (mi << 4) + ((lane >> 4) << 2);
    #pragma unroll
    for (int ni = 0; ni < 4; ++ni) {
      int col = n0 + (wn << 6) + (ni << 4) + (lane & 15);
      f32x4 v = acc[mi][ni];
      #pragma unroll
      for (int rr = 0; rr < 4; ++rr) {
        size_t idx = ((size_t)bz * 1024 + rbase + rr) * 1024 + col;
        if (ADDX) C[idx] = v[rr] + X[idx];
        else      C[idx] = v[rr];
      }
    }
  }
}

// ---------------- Kernel 3: row softmax, P bf16 in place ---------------------
__global__ __launch_bounds__(256) void softmax_rows(float* __restrict__ S)
{
  size_t rowi = blockIdx.x;
  float* srow = S + rowi * 1024;
  int t = threadIdx.x;
  float4 v = ((const float4*)srow)[t];
  float m = fmaxf(fmaxf(v.x, v.y), fmaxf(v.z, v.w));
  #pragma unroll
  for (int off = 32; off > 0; off >>= 1) m = fmaxf(m, __shfl_xor(m, off));
  __shared__ float red[8];
  int wid = t >> 6, lane = t & 63;
  if (lane == 0) red[wid] = m;
  __syncthreads();
  m = fmaxf(fmaxf(red[0], red[1]), fmaxf(red[2], red[3]));
  float e0 = __expf(v.x - m), e1 = __expf(v.y - m);
  float e2 = __expf(v.z - m), e3 = __expf(v.w - m);
  float s = e0 + e1 + e2 + e3;
  #pragma unroll
  for (int off = 32; off > 0; off >>= 1) s += __shfl_xor(s, off);
  if (lane == 0) red[4 + wid] = s;
  __syncthreads();
  s = red[4] + red[5] + red[6] + red[7];
  float inv = 1.0f / s;
  union { ushort h[4]; uint2 q; } pk;
  pk.h[0] = f2bf(e0 * inv); pk.h[1] = f2bf(e1 * inv);
  pk.h[2] = f2bf(e2 * inv); pk.h[3] = f2bf(e3 * inv);
  ((uint2*)srow)[t] = pk.q;
}

// ---------------- Launch -----------------------------------------------------
extern "C" void kernel_launch(void* const* d_in, const int* in_sizes, int n_in,
                              void* d_out, int out_size, void* d_ws, size_t ws_size,
                              hipStream_t stream) {
  const float* x  = (const float*)d_in[0];
  const float* Wq = (const float*)d_in[1];
  const float* bq = (const float*)d_in[2];
  const float* Wk = (const float*)d_in[3];
  const float* bk = (const float*)d_in[4];
  const float* Wv = (const float*)d_in[5];
  const float* bv = (const float*)d_in[6];
  float* out = (float*)d_out;

  char* wsb = (char*)d_ws;
  ushort* Qt2 = (ushort*)wsb;                          // 12,582,912 B
  ushort* Kt2 = (ushort*)(wsb + 12582912);             // 12,582,912 B
  ushort* Vt  = (ushort*)(wsb + 25165824);             // 33,554,432 B
  float*  S   = (float*)(wsb + 58720256);              // 67,108,864 B (P in place)
  float*  wp2 = (float*)(wsb + 92274688);              // inside S, dead before gemm1
  float*  bpk = wp2 + 5120;

  prep_w<<<21, 256, 0, stream>>>(Wq, bq, Wk, bk, Wv, bv, wp2, bpk);
  proj8<<<1024, 320, 0, stream>>>(x, wp2, bpk, Qt2, Kt2, Vt);
  gemm_nt<384, false><<<1024, 256, 0, stream>>>(Qt2, 384, Kt2, 384, S, nullptr);
  softmax_rows<<<16384, 256, 0, stream>>>(S);
  gemm_nt<1024, true><<<1024, 256, 0, stream>>>((const ushort*)S, 2048, Vt, 1024, out, x);
}

// Round 12
// 145.753 us; speedup vs baseline: 1.8023x; 1.0710x over previous
//
#include <hip/hip_runtime.h>
#include <stdint.h>

typedef uint32_t u32;
typedef __attribute__((ext_vector_type(4))) float f32x4;
typedef __attribute__((ext_vector_type(8))) short short8;

#define NBATCH 16
#define NPIX   16384      // H*W
#define NPB    1048576    // per-batch flat elems (C*H*W = 1024*1024)

__device__ __forceinline__ ushort f2bf(float f) {
  u32 b = __builtin_bit_cast(u32, f);
  return (ushort)((b + 0x7FFFu + ((b >> 16) & 1u)) >> 16);
}
__device__ __forceinline__ float bf2f(ushort h) {
  return __builtin_bit_cast(float, (u32)h << 16);
}

// async global->LDS, 16B per lane. LDS dest must be wave-uniform base;
// HW scatters lane i at base + i*16. Global source is per-lane.
__device__ __forceinline__ void gload16(const void* g, void* l) {
  __builtin_amdgcn_global_load_lds(
      (const __attribute__((address_space(1))) u32*)g,
      (__attribute__((address_space(3))) u32*)l,
      16, 0, 0);
}

// ---------------- Kernel 0: pack weights -------------------------------------
// wp2[ch][o] = W[o][ch]  (80 floats per ch row; 80%16==0 so each wave's
// 16-dword group is 64B-aligned -> s_load_dwordx16). bpk[o] = bias.
__global__ void prep_w(const float* __restrict__ Wq, const float* __restrict__ bq,
                       const float* __restrict__ Wk, const float* __restrict__ bk,
                       const float* __restrict__ Wv, const float* __restrict__ bv,
                       float* __restrict__ wp2, float* __restrict__ bpk)
{
  int gid = blockIdx.x * 256 + threadIdx.x;
  if (gid < 5120) {
    int ch = gid / 80;
    int o = gid - ch * 80;
    float v = (o < 8) ? Wq[o * 64 + ch]
            : (o < 16) ? Wk[(o - 8) * 64 + ch]
                       : Wv[(o - 16) * 64 + ch];
    wp2[gid] = v;
  } else if (gid < 5200) {
    int o = gid - 5120;
    bpk[o] = (o < 8) ? bq[o] : (o < 16 ? bk[o - 8] : bv[o - 16]);
  }
}

// ---------------- Kernel 1: FUSED proj + transposes, async-staged x ----------
// Block = (batch b, 8-l chunk) = 128 px (16 tc strips x 8 l). 320 threads
// (5 waves). Phase 1: stage xs[64][128] fp32 via 2048 global_load_lds
// (no VGPR cost -> hundreds of loads in flight -> HBM latency hidden; the
// R11 bottleneck). Phase 2: wave w computes out-group w (w0: 8q+8k,
// w1..4: 16 V ch); lane owns px {2j,2j+1}; x from LDS (ds_read_b64),
// weights = 16 contiguous uniform floats/ch (s_load). Phase 3: epilogue in
// RE-USED LDS (qkl/vl union over xs): 128 threads write Qt2/Kt2 (verified
// split-bf16 packing) + Vt rows, all coalesced. LDS 32KB -> 5 blocks/CU.
__global__ __launch_bounds__(320) void proj9(
    const float* __restrict__ x, const float* __restrict__ wp2,
    const float* __restrict__ bpk,
    ushort* __restrict__ Qt2, ushort* __restrict__ Kt2,
    ushort* __restrict__ Vt)
{
  __shared__ __align__(16) char smem[32768];
  float* xs = (float*)smem;                       // [64][128]
  int t = threadIdx.x;
  int w = t >> 6, lane = t & 63;

  // XCD-chunk remap: 2048 blocks, 256 per XCD = 2 batches, consecutive l0.
  int g = blockIdx.x;
  int lin = (g & 7) * 256 + (g >> 3);
  int b = lin >> 7;
  int l0 = (lin & 127) << 3;
  const float* xb = x + (size_t)b * NPB + l0;

  // stage: slot f (16B) holds x[ch][tc*1024 + l0 + half*4 .. +4),
  // f = ch*32 + tc*2 + half -> xs linear [ch*128 + tc*8 + half*4).
  #pragma unroll
  for (int it = 0; it < 7; ++it) {
    int f0 = (it * 5 + w) * 64;
    if (f0 < 2048) {
      int f = f0 + lane;
      int ch = f >> 5, r2 = f & 31, tc = r2 >> 1, half = r2 & 1;
      gload16(xb + (size_t)ch * NPIX + tc * 1024 + half * 4, xs + f0 * 4);
    }
  }
  __syncthreads();   // drains vmcnt + barrier (m97 pattern)

  int ob = __builtin_amdgcn_readfirstlane(w * 16);
  float acc[16][2];
  #pragma unroll
  for (int o = 0; o < 16; ++o) { float bb = bpk[ob + o]; acc[o][0] = bb; acc[o][1] = bb; }

  for (int ch = 0; ch < 64; ++ch) {
    float2 xv = *(const float2*)&xs[ch * 128 + 2 * lane];
    const float* wr = wp2 + ch * 80 + ob;   // uniform, 16 contiguous dwords
    #pragma unroll
    for (int o = 0; o < 16; ++o) {
      float wo = wr[o];
      acc[o][0] += wo * xv.x;
      acc[o][1] += wo * xv.y;
    }
  }
  __syncthreads();   // all xs reads done before epilogue overwrites smem

  float*  qkl = (float*)smem;              // [16][132] fp32
  ushort* vl  = (ushort*)(smem + 16 * 132 * 4);  // [64][136] bf16

  if (w == 0) {
    #pragma unroll
    for (int o = 0; o < 16; ++o) {
      qkl[o * 132 + 2 * lane]     = acc[o][0];
      qkl[o * 132 + 2 * lane + 1] = acc[o][1];
    }
  } else {
    int cb = ob - 16;
    #pragma unroll
    for (int o = 0; o < 16; ++o) {
      u32 pk2 = (u32)f2bf(acc[o][0]) | ((u32)f2bf(acc[o][1]) << 16);
      *(u32*)&vl[(cb + o) * 136 + 2 * lane] = pk2;
    }
  }
  __syncthreads();

  if (t < 128) {
    int l = t >> 4, tcc = t & 15;
    size_t lrow = (size_t)b * 1024 + l0 + l;
    int px = tcc * 8 + l;

    // Q/K split bf16 (verified packing): Q = [qh][ql][qh], K = [kh][kh][kl]
    // so dot = qh*kh + ql*kh + qh*kl (drops only ~2e-4 ql*kl term).
    union { ushort s[8]; uint4 v; } qh, ql, kh, kl;
    #pragma unroll
    for (int o = 0; o < 8; ++o) {
      float qv = qkl[o * 132 + px];
      ushort h = f2bf(qv);
      qh.s[o] = h; ql.s[o] = f2bf(qv - bf2f(h));
      float kv = qkl[(8 + o) * 132 + px];
      h = f2bf(kv);
      kh.s[o] = h; kl.s[o] = f2bf(kv - bf2f(h));
    }
    ushort* qrow = Qt2 + lrow * 384 + tcc * 8;
    *(uint4*)qrow         = qh.v;
    *(uint4*)(qrow + 128) = ql.v;
    *(uint4*)(qrow + 256) = qh.v;
    ushort* krow = Kt2 + lrow * 384 + tcc * 8;
    *(uint4*)krow         = kh.v;
    *(uint4*)(krow + 128) = kh.v;
    *(uint4*)(krow + 256) = kl.v;

    // Vt row: Vt[lrow][c2*16+tt] = v[c2][tt*1024 + l0+l] = vl[c2][tt*8+l]
    ushort* vrow = Vt + lrow * 1024;
    #pragma unroll
    for (int it = 0; it < 4; ++it) {
      int c2 = (it << 4) + tcc;
      union { ushort s[16]; uint4 q[2]; } ov;
      #pragma unroll
      for (int tt = 0; tt < 16; ++tt)
        ov.s[tt] = vl[c2 * 136 + tt * 8 + l];
      *(uint4*)(vrow + c2 * 16)     = ov.q[0];
      *(uint4*)(vrow + c2 * 16 + 8) = ov.q[1];
    }
  }
}

// ---------------- Kernels 2/4: NT bf16 MFMA GEMM (m97 + src-side swizzle) ----
// C[i][j] = sum_k A[i][k]*B[j][k]; per-batch 1024x1024, tile 128x128, BK=64.
// global_load_lds width-16 staging, LINEAR LDS dest, global SOURCE chunk
// XOR-pre-swizzled (chunk' = chunk ^ (row&7)) with the same XOR on fragment
// reads -> bank-conflict-free. XCD-chunked 1D grid (2 batches per XCD).
template<int KTOT, bool ADDX>
__global__ __launch_bounds__(256) void gemm_nt(
    const ushort* __restrict__ A, int lda,
    const ushort* __restrict__ B, int ldb,
    float* __restrict__ C, const float* __restrict__ X)
{
  __shared__ ushort Asm[128 * 64];
  __shared__ ushort Bsm[128 * 64];
  int t = threadIdx.x;

  // bijective XCD-chunk remap (1024 blocks, 8 XCDs, 128 each = 2 batches)
  int g = blockIdx.x;
  int lin = (g & 7) * 128 + (g >> 3);
  int bz = lin >> 6;
  int by = (lin >> 3) & 7;
  int bx = lin & 7;
  int m0 = by << 7, n0 = bx << 7;

  const ushort* Ab = A + (size_t)bz * 1024 * lda;
  const ushort* Bb = B + (size_t)bz * 1024 * ldb;
  int wid = t >> 6, lane = t & 63;
  int wm = wid >> 1, wn = wid & 1;

  int swc = (t & 7) ^ ((t >> 3) & 7);
  const ushort* pa = Ab + (size_t)(m0 + (t >> 3)) * lda + swc * 8;
  const ushort* pb = Bb + (size_t)(n0 + (t >> 3)) * ldb + swc * 8;
  ushort* la0 = Asm + (size_t)(t >> 6) * 512;   // wave base, elems (1024 B)
  ushort* lb0 = Bsm + (size_t)(t >> 6) * 512;

  f32x4 acc[4][4] = {};

  for (int k0 = 0; k0 < KTOT; k0 += 64) {
    __syncthreads();                 // previous compute done before overwrite
    #pragma unroll
    for (int i = 0; i < 4; ++i)
      gload16(pa + (size_t)i * 32 * lda + k0, la0 + i * 2048);
    #pragma unroll
    for (int i = 0; i < 4; ++i)
      gload16(pb + (size_t)i * 32 * ldb + k0, lb0 + i * 2048);
    __syncthreads();                 // drains vmcnt (lds) + barrier
    #pragma unroll
    for (int kk = 0; kk < 2; ++kk) {
      short8 af[4], bfr[4];
      #pragma unroll
      for (int mi = 0; mi < 4; ++mi) {
        int rr = (wm << 6) + (mi << 4) + (lane & 15);
        af[mi] = __builtin_bit_cast(short8,
            ((const uint4*)Asm)[rr * 8 + ((kk * 4 + (lane >> 4)) ^ (rr & 7))]);
      }
      #pragma unroll
      for (int ni = 0; ni < 4; ++ni) {
        int rr = (wn << 6) + (ni << 4) + (lane & 15);
        bfr[ni] = __builtin_bit_cast(short8,
            ((const uint4*)Bsm)[rr * 8 + ((kk * 4 + (lane >> 4)) ^ (rr & 7))]);
      }
      #pragma unroll
      for (int mi = 0; mi < 4; ++mi)
        #pragma unroll
        for (int ni = 0; ni < 4; ++ni)
          acc[mi][ni] = __builtin_amdgcn_mfma_f32_16x16x32_bf16(
              af[mi], bfr[ni], acc[mi][ni], 0, 0, 0);
    }
  }

  #pragma unroll
  for (int mi = 0; mi < 4; ++mi) {
    int rbase = m0 + (wm << 6) + (mi << 4) + ((lane >> 4) << 2);
    #pragma unroll
    for (int ni = 0; ni < 4; ++ni) {
      int col = n0 + (wn << 6) + (ni << 4) + (lane & 15);
      f32x4 v = acc[mi][ni];
      #pragma unroll
      for (int rr = 0; rr < 4; ++rr) {
        size_t idx = ((size_t)bz * 1024 + rbase + rr) * 1024 + col;
        if (ADDX) C[idx] = v[rr] + X[idx];
        else      C[idx] = v[rr];
      }
    }
  }
}

// ---------------- Kernel 3: row softmax, P bf16 in place ---------------------
__global__ __launch_bounds__(256) void softmax_rows(float* __restrict__ S)
{
  size_t rowi = blockIdx.x;
  float* srow = S + rowi * 1024;
  int t = threadIdx.x;
  float4 v = ((const float4*)srow)[t];
  float m = fmaxf(fmaxf(v.x, v.y), fmaxf(v.z, v.w));
  #pragma unroll
  for (int off = 32; off > 0; off >>= 1) m = fmaxf(m, __shfl_xor(m, off));
  __shared__ float red[8];
  int wid = t >> 6, lane = t & 63;
  if (lane == 0) red[wid] = m;
  __syncthreads();
  m = fmaxf(fmaxf(red[0], red[1]), fmaxf(red[2], red[3]));
  float e0 = __expf(v.x - m), e1 = __expf(v.y - m);
  float e2 = __expf(v.z - m), e3 = __expf(v.w - m);
  float s = e0 + e1 + e2 + e3;
  #pragma unroll
  for (int off = 32; off > 0; off >>= 1) s += __shfl_xor(s, off);
  if (lane == 0) red[4 + wid] = s;
  __syncthreads();
  s = red[4] + red[5] + red[6] + red[7];
  float inv = 1.0f / s;
  union { ushort h[4]; uint2 q; } pk;
  pk.h[0] = f2bf(e0 * inv); pk.h[1] = f2bf(e1 * inv);
  pk.h[2] = f2bf(e2 * inv); pk.h[3] = f2bf(e3 * inv);
  ((uint2*)srow)[t] = pk.q;
}

// ---------------- Launch -----------------------------------------------------
extern "C" void kernel_launch(void* const* d_in, const int* in_sizes, int n_in,
                              void* d_out, int out_size, void* d_ws, size_t ws_size,
                              hipStream_t stream) {
  const float* x  = (const float*)d_in[0];
  const float* Wq = (const float*)d_in[1];
  const float* bq = (const float*)d_in[2];
  const float* Wk = (const float*)d_in[3];
  const float* bk = (const float*)d_in[4];
  const float* Wv = (const float*)d_in[5];
  const float* bv = (const float*)d_in[6];
  float* out = (float*)d_out;

  char* wsb = (char*)d_ws;
  ushort* Qt2 = (ushort*)wsb;                          // 12,582,912 B
  ushort* Kt2 = (ushort*)(wsb + 12582912);             // 12,582,912 B
  ushort* Vt  = (ushort*)(wsb + 25165824);             // 33,554,432 B
  float*  S   = (float*)(wsb + 58720256);              // 67,108,864 B (P in place)
  float*  wp2 = (float*)(wsb + 92274688);              // inside S, dead before gemm1
  float*  bpk = wp2 + 5120;

  prep_w<<<21, 256, 0, stream>>>(Wq, bq, Wk, bk, Wv, bv, wp2, bpk);
  proj9<<<2048, 320, 0, stream>>>(x, wp2, bpk, Qt2, Kt2, Vt);
  gemm_nt<384, false><<<1024, 256, 0, stream>>>(Qt2, 384, Kt2, 384, S, nullptr);
  softmax_rows<<<16384, 256, 0, stream>>>(S);
  gemm_nt<1024, true><<<1024, 256, 0, stream>>>((const ushort*)S, 2048, Vt, 1024, out, x);
}

// Round 13
// 129.721 us; speedup vs baseline: 2.0250x; 1.1236x over previous
//
#include <hip/hip_runtime.h>
#include <stdint.h>

typedef uint32_t u32;
typedef __attribute__((ext_vector_type(4))) float f32x4;
typedef __attribute__((ext_vector_type(8))) short short8;

#define NBATCH 16
#define NPIX   16384      // H*W
#define NPB    1048576    // per-batch flat elems (C*H*W = 1024*1024)

__device__ __forceinline__ ushort f2bf(float f) {
  u32 b = __builtin_bit_cast(u32, f);
  return (ushort)((b + 0x7FFFu + ((b >> 16) & 1u)) >> 16);
}
__device__ __forceinline__ float bf2f(ushort h) {
  return __builtin_bit_cast(float, (u32)h << 16);
}

// async global->LDS, 16B per lane. LDS dest must be wave-uniform base;
// HW scatters lane i at base + i*16. Global source is per-lane.
__device__ __forceinline__ void gload16(const void* g, void* l) {
  __builtin_amdgcn_global_load_lds(
      (const __attribute__((address_space(1))) u32*)g,
      (__attribute__((address_space(3))) u32*)l,
      16, 0, 0);
}

// ---------------- Kernel 0: pack weights for MFMA-proj -----------------------
// Wpk[96][128] bf16: rows 0..15 = q,k: cols[0:64]=Wh (round), [64:128]=Wl
// (W - Wh, exact split). Rows 16..79 = v: cols[0:64]=bf16(Wv), rest 0.
// Rows 80..95 zero pad. bpk[80] = biases (q,k,v order).
__global__ void prep_w2(const float* __restrict__ Wq, const float* __restrict__ bq,
                        const float* __restrict__ Wk, const float* __restrict__ bk,
                        const float* __restrict__ Wv, const float* __restrict__ bv,
                        ushort* __restrict__ Wpk, float* __restrict__ bpk)
{
  int gid = blockIdx.x * 256 + threadIdx.x;
  if (gid < 12288) {
    int m = gid >> 7, kk = gid & 127;
    int ch = kk & 63;
    ushort outv = 0;
    if (m < 8) {
      float wv = Wq[m * 64 + ch];
      ushort h = f2bf(wv);
      outv = (kk < 64) ? h : f2bf(wv - bf2f(h));
    } else if (m < 16) {
      float wv = Wk[(m - 8) * 64 + ch];
      ushort h = f2bf(wv);
      outv = (kk < 64) ? h : f2bf(wv - bf2f(h));
    } else if (m < 80) {
      outv = (kk < 64) ? f2bf(Wv[(m - 16) * 64 + ch]) : (ushort)0;
    }
    Wpk[gid] = outv;
  } else if (gid < 12368) {
    int o = gid - 12288;
    bpk[o] = (o < 8) ? bq[o] : (o < 16 ? bk[o - 8] : bv[o - 16]);
  }
}

// ---------------- Kernel 1: MFMA proj + fused transposes ---------------------
// Block = (batch b, 8-l chunk) = 128 px. 256 threads (4 waves). Phase 1:
// stage xs[64][128] fp32 via global_load_lds (proj9 map, HBM-saturating).
// Phase 2: per wave, 2 N-tiles (16 px each). B-frags built in-register from
// xs: xh = TRUNC-split high bf16, xl = x - xh (exact), packed to short8.
// q/k (M-tile 0) = Wh*xh + Wh*xl + Wl*xh (6 MFMA); v (M-tiles 1-4) =
// Wv*xh (2 MFMA each). A-frags preloaded from global Wpk (L2-hot). Bias via
// acc init. Phase 3: proj9's VERIFIED epilogue verbatim (qkl/vl LDS alias
// over xs -> Qt2/Kt2 split-bf16 + Vt coalesced rows).
__global__ __launch_bounds__(256) void proj10(
    const float* __restrict__ x, const ushort* __restrict__ Wpk,
    const float* __restrict__ bpk,
    ushort* __restrict__ Qt2, ushort* __restrict__ Kt2,
    ushort* __restrict__ Vt)
{
  __shared__ __align__(16) char smem[32768];
  float* xs = (float*)smem;                       // [64][128]
  int t = threadIdx.x;
  int w = t >> 6, lane = t & 63;
  int l15 = lane & 15, l4 = lane >> 4;

  // XCD-chunk remap: 2048 blocks, 256 per XCD = 2 batches, consecutive l0.
  int g = blockIdx.x;
  int lin = (g & 7) * 256 + (g >> 3);
  int b = lin >> 7;
  int l0 = (lin & 127) << 3;
  const float* xb = x + (size_t)b * NPB + l0;

  // stage: slot f (16B) = x[ch][tc*1024 + l0 + half*4 ..+4), f = ch*32+tc*2+half
  // -> xs[ch][pxi], pxi = tc*8 + half*4 + e  (proj9-verified map)
  #pragma unroll
  for (int it = 0; it < 8; ++it) {
    int f0 = (it * 4 + w) * 64;
    int f = f0 + lane;
    int ch = f >> 5, r2 = f & 31, tc = r2 >> 1, half = r2 & 1;
    gload16(xb + (size_t)ch * NPIX + tc * 1024 + half * 4, xs + f0 * 4);
  }

  // A-frags (global, issued pre-barrier): frag(mt,kc)[lane] =
  // Wpk[mt*16 + l15][kc*32 + l4*8 ..+8]
  const uint4* Wp4 = (const uint4*)Wpk;   // row stride 16 uint4
  uint4 Afrag[12];
  #pragma unroll
  for (int kc = 0; kc < 4; ++kc)
    Afrag[kc] = Wp4[l15 * 16 + kc * 4 + l4];
  #pragma unroll
  for (int mt = 1; mt < 5; ++mt)
    #pragma unroll
    for (int kc = 0; kc < 2; ++kc)
      Afrag[2 + mt * 2 + kc] = Wp4[(mt * 16 + l15) * 16 + kc * 4 + l4];

  // acc init = bias (C row m = mt*16 + l4*4 + r)
  f32x4 acc[5][2];
  #pragma unroll
  for (int mt = 0; mt < 5; ++mt) {
    f32x4 bv4;
    #pragma unroll
    for (int r = 0; r < 4; ++r) bv4[r] = bpk[mt * 16 + l4 * 4 + r];
    acc[mt][0] = bv4; acc[mt][1] = bv4;
  }

  __syncthreads();   // drains gloads + A-frag loads (m97 pattern)

  #pragma unroll
  for (int i = 0; i < 2; ++i) {
    int px = (w * 2 + i) * 16 + l15;
    // 16 fp32 per lane: ch = kc*32 + l4*8 + j (xl reuses the same values)
    u32 xr[16];
    #pragma unroll
    for (int kc = 0; kc < 2; ++kc)
      #pragma unroll
      for (int j = 0; j < 8; ++j)
        xr[kc * 8 + j] = ((const u32*)xs)[(kc * 32 + l4 * 8 + j) * 128 + px];
    uint4 bxh[2], bxl[2];
    #pragma unroll
    for (int kc = 0; kc < 2; ++kc)
      #pragma unroll
      for (int p = 0; p < 4; ++p) {
        u32 a = xr[kc * 8 + 2 * p], c = xr[kc * 8 + 2 * p + 1];
        ((u32*)&bxh[kc])[p] = (a >> 16) | (c & 0xFFFF0000u);
        float fa = __builtin_bit_cast(float, a) -
                   __builtin_bit_cast(float, a & 0xFFFF0000u);
        float fc = __builtin_bit_cast(float, c) -
                   __builtin_bit_cast(float, c & 0xFFFF0000u);
        u32 la = __builtin_bit_cast(u32, fa), lc = __builtin_bit_cast(u32, fc);
        ((u32*)&bxl[kc])[p] = (la >> 16) | (lc & 0xFFFF0000u);
      }
    short8 h0 = __builtin_bit_cast(short8, bxh[0]);
    short8 h1 = __builtin_bit_cast(short8, bxh[1]);
    short8 s0 = __builtin_bit_cast(short8, bxl[0]);
    short8 s1 = __builtin_bit_cast(short8, bxl[1]);
    // q/k: Wh*xh + Wh*xl + Wl*xh
    acc[0][i] = __builtin_amdgcn_mfma_f32_16x16x32_bf16(
        __builtin_bit_cast(short8, Afrag[0]), h0, acc[0][i], 0, 0, 0);
    acc[0][i] = __builtin_amdgcn_mfma_f32_16x16x32_bf16(
        __builtin_bit_cast(short8, Afrag[1]), h1, acc[0][i], 0, 0, 0);
    acc[0][i] = __builtin_amdgcn_mfma_f32_16x16x32_bf16(
        __builtin_bit_cast(short8, Afrag[0]), s0, acc[0][i], 0, 0, 0);
    acc[0][i] = __builtin_amdgcn_mfma_f32_16x16x32_bf16(
        __builtin_bit_cast(short8, Afrag[1]), s1, acc[0][i], 0, 0, 0);
    acc[0][i] = __builtin_amdgcn_mfma_f32_16x16x32_bf16(
        __builtin_bit_cast(short8, Afrag[2]), h0, acc[0][i], 0, 0, 0);
    acc[0][i] = __builtin_amdgcn_mfma_f32_16x16x32_bf16(
        __builtin_bit_cast(short8, Afrag[3]), h1, acc[0][i], 0, 0, 0);
    // v: Wv*xh
    #pragma unroll
    for (int mt = 1; mt < 5; ++mt) {
      acc[mt][i] = __builtin_amdgcn_mfma_f32_16x16x32_bf16(
          __builtin_bit_cast(short8, Afrag[2 + mt * 2]), h0, acc[mt][i], 0, 0, 0);
      acc[mt][i] = __builtin_amdgcn_mfma_f32_16x16x32_bf16(
          __builtin_bit_cast(short8, Afrag[3 + mt * 2]), h1, acc[mt][i], 0, 0, 0);
    }
  }
  __syncthreads();   // all xs reads done before epilogue overwrites smem

  float*  qkl = (float*)smem;                    // [16][132]
  ushort* vl  = (ushort*)(smem + 16 * 132 * 4);  // [64][136]
  #pragma unroll
  for (int i = 0; i < 2; ++i) {
    int px = (w * 2 + i) * 16 + l15;
    #pragma unroll
    for (int r = 0; r < 4; ++r)
      qkl[(l4 * 4 + r) * 132 + px] = acc[0][i][r];
    #pragma unroll
    for (int mt = 1; mt < 5; ++mt)
      #pragma unroll
      for (int r = 0; r < 4; ++r)
        vl[((mt - 1) * 16 + l4 * 4 + r) * 136 + px] = f2bf(acc[mt][i][r]);
  }
  __syncthreads();

  if (t < 128) {
    int l = t >> 4, tcc = t & 15;
    size_t lrow = (size_t)b * 1024 + l0 + l;
    int px = tcc * 8 + l;

    // Q/K split bf16 (verified packing): Q = [qh][ql][qh], K = [kh][kh][kl]
    // so dot = qh*kh + ql*kh + qh*kl (drops only ~2e-4 ql*kl term).
    union { ushort s[8]; uint4 v; } qh, ql, kh, kl;
    #pragma unroll
    for (int o = 0; o < 8; ++o) {
      float qv = qkl[o * 132 + px];
      ushort h = f2bf(qv);
      qh.s[o] = h; ql.s[o] = f2bf(qv - bf2f(h));
      float kv = qkl[(8 + o) * 132 + px];
      h = f2bf(kv);
      kh.s[o] = h; kl.s[o] = f2bf(kv - bf2f(h));
    }
    ushort* qrow = Qt2 + lrow * 384 + tcc * 8;
    *(uint4*)qrow         = qh.v;
    *(uint4*)(qrow + 128) = ql.v;
    *(uint4*)(qrow + 256) = qh.v;
    ushort* krow = Kt2 + lrow * 384 + tcc * 8;
    *(uint4*)krow         = kh.v;
    *(uint4*)(krow + 128) = kh.v;
    *(uint4*)(krow + 256) = kl.v;

    // Vt row: Vt[lrow][c2*16+tt] = v[c2][tt*1024 + l0+l] = vl[c2][tt*8+l]
    ushort* vrow = Vt + lrow * 1024;
    #pragma unroll
    for (int it = 0; it < 4; ++it) {
      int c2 = (it << 4) + tcc;
      union { ushort s[16]; uint4 q[2]; } ov;
      #pragma unroll
      for (int tt = 0; tt < 16; ++tt)
        ov.s[tt] = vl[c2 * 136 + tt * 8 + l];
      *(uint4*)(vrow + c2 * 16)     = ov.q[0];
      *(uint4*)(vrow + c2 * 16 + 8) = ov.q[1];
    }
  }
}

// ---------------- Kernels 2/4: NT bf16 MFMA GEMM (m97 + src-side swizzle) ----
// C[i][j] = sum_k A[i][k]*B[j][k]; per-batch 1024x1024, tile 128x128, BK=64.
// global_load_lds width-16 staging, LINEAR LDS dest, global SOURCE chunk
// XOR-pre-swizzled (chunk' = chunk ^ (row&7)) with the same XOR on fragment
// reads -> bank-conflict-free. XCD-chunked 1D grid (2 batches per XCD).
template<int KTOT, bool ADDX>
__global__ __launch_bounds__(256) void gemm_nt(
    const ushort* __restrict__ A, int lda,
    const ushort* __restrict__ B, int ldb,
    float* __restrict__ C, const float* __restrict__ X)
{
  __shared__ ushort Asm[128 * 64];
  __shared__ ushort Bsm[128 * 64];
  int t = threadIdx.x;

  // bijective XCD-chunk remap (1024 blocks, 8 XCDs, 128 each = 2 batches)
  int g = blockIdx.x;
  int lin = (g & 7) * 128 + (g >> 3);
  int bz = lin >> 6;
  int by = (lin >> 3) & 7;
  int bx = lin & 7;
  int m0 = by << 7, n0 = bx << 7;

  const ushort* Ab = A + (size_t)bz * 1024 * lda;
  const ushort* Bb = B + (size_t)bz * 1024 * ldb;
  int wid = t >> 6, lane = t & 63;
  int wm = wid >> 1, wn = wid & 1;

  int swc = (t & 7) ^ ((t >> 3) & 7);
  const ushort* pa = Ab + (size_t)(m0 + (t >> 3)) * lda + swc * 8;
  const ushort* pb = Bb + (size_t)(n0 + (t >> 3)) * ldb + swc * 8;
  ushort* la0 = Asm + (size_t)(t >> 6) * 512;   // wave base, elems (1024 B)
  ushort* lb0 = Bsm + (size_t)(t >> 6) * 512;

  f32x4 acc[4][4] = {};

  for (int k0 = 0; k0 < KTOT; k0 += 64) {
    __syncthreads();                 // previous compute done before overwrite
    #pragma unroll
    for (int i = 0; i < 4; ++i)
      gload16(pa + (size_t)i * 32 * lda + k0, la0 + i * 2048);
    #pragma unroll
    for (int i = 0; i < 4; ++i)
      gload16(pb + (size_t)i * 32 * ldb + k0, lb0 + i * 2048);
    __syncthreads();                 // drains vmcnt (lds) + barrier
    #pragma unroll
    for (int kk = 0; kk < 2; ++kk) {
      short8 af[4], bfr[4];
      #pragma unroll
      for (int mi = 0; mi < 4; ++mi) {
        int rr = (wm << 6) + (mi << 4) + (lane & 15);
        af[mi] = __builtin_bit_cast(short8,
            ((const uint4*)Asm)[rr * 8 + ((kk * 4 + (lane >> 4)) ^ (rr & 7))]);
      }
      #pragma unroll
      for (int ni = 0; ni < 4; ++ni) {
        int rr = (wn << 6) + (ni << 4) + (lane & 15);
        bfr[ni] = __builtin_bit_cast(short8,
            ((const uint4*)Bsm)[rr * 8 + ((kk * 4 + (lane >> 4)) ^ (rr & 7))]);
      }
      #pragma unroll
      for (int mi = 0; mi < 4; ++mi)
        #pragma unroll
        for (int ni = 0; ni < 4; ++ni)
          acc[mi][ni] = __builtin_amdgcn_mfma_f32_16x16x32_bf16(
              af[mi], bfr[ni], acc[mi][ni], 0, 0, 0);
    }
  }

  #pragma unroll
  for (int mi = 0; mi < 4; ++mi) {
    int rbase = m0 + (wm << 6) + (mi << 4) + ((lane >> 4) << 2);
    #pragma unroll
    for (int ni = 0; ni < 4; ++ni) {
      int col = n0 + (wn << 6) + (ni << 4) + (lane & 15);
      f32x4 v = acc[mi][ni];
      #pragma unroll
      for (int rr = 0; rr < 4; ++rr) {
        size_t idx = ((size_t)bz * 1024 + rbase + rr) * 1024 + col;
        if (ADDX) C[idx] = v[rr] + X[idx];
        else      C[idx] = v[rr];
      }
    }
  }
}

// ---------------- Kernel 3: row softmax, P bf16 in place ---------------------
__global__ __launch_bounds__(256) void softmax_rows(float* __restrict__ S)
{
  size_t rowi = blockIdx.x;
  float* srow = S + rowi * 1024;
  int t = threadIdx.x;
  float4 v = ((const float4*)srow)[t];
  float m = fmaxf(fmaxf(v.x, v.y), fmaxf(v.z, v.w));
  #pragma unroll
  for (int off = 32; off > 0; off >>= 1) m = fmaxf(m, __shfl_xor(m, off));
  __shared__ float red[8];
  int wid = t >> 6, lane = t & 63;
  if (lane == 0) red[wid] = m;
  __syncthreads();
  m = fmaxf(fmaxf(red[0], red[1]), fmaxf(red[2], red[3]));
  float e0 = __expf(v.x - m), e1 = __expf(v.y - m);
  float e2 = __expf(v.z - m), e3 = __expf(v.w - m);
  float s = e0 + e1 + e2 + e3;
  #pragma unroll
  for (int off = 32; off > 0; off >>= 1) s += __shfl_xor(s, off);
  if (lane == 0) red[4 + wid] = s;
  __syncthreads();
  s = red[4] + red[5] + red[6] + red[7];
  float inv = 1.0f / s;
  union { ushort h[4]; uint2 q; } pk;
  pk.h[0] = f2bf(e0 * inv); pk.h[1] = f2bf(e1 * inv);
  pk.h[2] = f2bf(e2 * inv); pk.h[3] = f2bf(e3 * inv);
  ((uint2*)srow)[t] = pk.q;
}

// ---------------- Launch -----------------------------------------------------
extern "C" void kernel_launch(void* const* d_in, const int* in_sizes, int n_in,
                              void* d_out, int out_size, void* d_ws, size_t ws_size,
                              hipStream_t stream) {
  const float* x  = (const float*)d_in[0];
  const float* Wq = (const float*)d_in[1];
  const float* bq = (const float*)d_in[2];
  const float* Wk = (const float*)d_in[3];
  const float* bk = (const float*)d_in[4];
  const float* Wv = (const float*)d_in[5];
  const float* bv = (const float*)d_in[6];
  float* out = (float*)d_out;

  char* wsb = (char*)d_ws;
  ushort* Qt2 = (ushort*)wsb;                          // 12,582,912 B
  ushort* Kt2 = (ushort*)(wsb + 12582912);             // 12,582,912 B
  ushort* Vt  = (ushort*)(wsb + 25165824);             // 33,554,432 B
  float*  S   = (float*)(wsb + 58720256);              // 67,108,864 B (P in place)
  ushort* Wpk = (ushort*)(wsb + 92274688);             // inside S, dead before gemm1
  float*  bpk = (float*)(wsb + 92274688 + 24576);

  prep_w2<<<49, 256, 0, stream>>>(Wq, bq, Wk, bk, Wv, bv, Wpk, bpk);
  proj10<<<2048, 256, 0, stream>>>(x, Wpk, bpk, Qt2, Kt2, Vt);
  gemm_nt<384, false><<<1024, 256, 0, stream>>>(Qt2, 384, Kt2, 384, S, nullptr);
  softmax_rows<<<16384, 256, 0, stream>>>(S);
  gemm_nt<1024, true><<<1024, 256, 0, stream>>>((const ushort*)S, 2048, Vt, 1024, out, x);
}